// Round 8
// baseline (760.138 us; speedup 1.0000x reference)
//
#include <hip/hip_runtime.h>
#include <hip/hip_fp16.h>

// Graph_NN: 3-layer SAGE (gcn aggregator), N=100000, E=1600000, D=128, fp32.
// R8: every layer is now project-then-aggregate:
//   layer l: g = h @ W[l]  (GEMM, sequential fp16)   [layer1: embW = emb@W1, V rows]
//            h' = relu(inv*(g[v] + sum_u g[u]) + b[l])  (fused agg epilogue)
// -> x32 intermediate deleted (agg writes 25.6MB fp16, gemm reads 25.6MB fp16).
// k_fill writes single 4B src/edge (ann re-derived from L2-hot ann[]).
// CSR rows sorted by src so concurrent waves sweep src-space in loose
// lockstep -> better per-XCD L2 hit rate on the dominant random g reads.

#define D 128

// ---------- CSR build ----------
__global__ void k_count(const int* __restrict__ dst, int* __restrict__ deg, int E) {
    int e = blockIdx.x * blockDim.x + threadIdx.x;
    if (e < E) atomicAdd(&deg[dst[e]], 1);
}

__global__ void k_bsum(const int* __restrict__ deg, int* __restrict__ bsum, int n) {
    __shared__ int s[256];
    int t = threadIdx.x, i = blockIdx.x * 256 + t;
    s[t] = (i < n) ? deg[i] : 0;
    __syncthreads();
    for (int off = 128; off > 0; off >>= 1) { if (t < off) s[t] += s[t + off]; __syncthreads(); }
    if (t == 0) bsum[blockIdx.x] = s[0];
}

__global__ void k_scanb(int* __restrict__ bsum, int nb, int* __restrict__ row_ptr, int N, int E) {
    __shared__ int s[512];
    int t = threadIdx.x;
    int v = (t < nb) ? bsum[t] : 0;
    s[t] = v;
    __syncthreads();
    for (int off = 1; off < 512; off <<= 1) {
        int x = (t >= off) ? s[t - off] : 0;
        __syncthreads();
        s[t] += x;
        __syncthreads();
    }
    if (t < nb) bsum[t] = s[t] - v;          // exclusive prefix
    if (t == 0) row_ptr[N] = E;
}

__global__ void k_scan_local(const int* __restrict__ deg, const int* __restrict__ bpre,
                             int* __restrict__ row_ptr, int n) {
    __shared__ int s[256];
    int t = threadIdx.x, i = blockIdx.x * 256 + t;
    int v = (i < n) ? deg[i] : 0;
    s[t] = v;
    __syncthreads();
    for (int off = 1; off < 256; off <<= 1) {
        int x = (t >= off) ? s[t - off] : 0;
        __syncthreads();
        s[t] += x;
        __syncthreads();
    }
    if (i < n) row_ptr[i] = bpre[blockIdx.x] + s[t] - v;   // exclusive
}

// fill eidx[pos] = src, grouped by dst — single 4B scattered write per edge
__global__ void k_fill(const int* __restrict__ src, const int* __restrict__ dst,
                       const int* __restrict__ row_ptr, int* __restrict__ cur,
                       int* __restrict__ eidx, int E) {
    int e = blockIdx.x * blockDim.x + threadIdx.x;
    if (e >= E) return;
    int d = dst[e];
    int pos = atomicAdd(&cur[d], 1);
    eidx[row_ptr[d] + pos] = src[e];
}

// sort each row's src list ascending (one thread per node; rows avg 16)
__global__ void k_sort(const int* __restrict__ row_ptr, int* __restrict__ eidx, int n) {
    int v = blockIdx.x * blockDim.x + threadIdx.x;
    if (v >= n) return;
    int b = row_ptr[v], e = row_ptr[v + 1];
    for (int i = b + 1; i < e; i++) {
        int key = eidx[i];
        int j = i - 1;
        while (j >= b && eidx[j] > key) { eidx[j + 1] = eidx[j]; j--; }
        eidx[j + 1] = key;
    }
}

// ---------- small plain GEMM: out = x @ W (fp32 in/out, V rows) ------------
__global__ __launch_bounds__(256) void k_gemm_plain(
    const float* __restrict__ x, const float* __restrict__ W,
    float* __restrict__ out, int n, int ntiles) {
    __shared__ float Wl[128 * 128];
    __shared__ float Xs[128 * 132];
    int tid = threadIdx.x;

    const float4* W4 = (const float4*)W;
    float4* Wl4 = (float4*)Wl;
    #pragma unroll
    for (int i = 0; i < 16; i++) Wl4[tid + i * 256] = W4[tid + i * 256];

    int c0 = (tid & 15) * 8;
    int r0 = (tid >> 4) * 8;
    int sr = tid >> 1;
    int sq = (tid & 1) * 16;
    const float4* x4p = (const float4*)x;

    for (int tile = blockIdx.x; tile < ntiles; tile += gridDim.x) {
        __syncthreads();
        {
            int grow = tile * 128 + sr;
            if (grow < n) {
                #pragma unroll
                for (int j = 0; j < 16; j++) {
                    int q = sq + j;
                    float4 v = x4p[(size_t)grow * 32 + q];
                    Xs[(q * 4 + 0) * 132 + sr] = v.x;
                    Xs[(q * 4 + 1) * 132 + sr] = v.y;
                    Xs[(q * 4 + 2) * 132 + sr] = v.z;
                    Xs[(q * 4 + 3) * 132 + sr] = v.w;
                }
            }
        }
        __syncthreads();

        float acc[8][8] = {};
        #pragma unroll 2
        for (int k = 0; k < 128; k++) {
            float4 xa = *(const float4*)&Xs[k * 132 + r0];
            float4 xb = *(const float4*)&Xs[k * 132 + r0 + 4];
            float4 wa = *(const float4*)&Wl[k * 128 + c0];
            float4 wb = *(const float4*)&Wl[k * 128 + c0 + 4];
            float xr[8] = {xa.x, xa.y, xa.z, xa.w, xb.x, xb.y, xb.z, xb.w};
            float wc[8] = {wa.x, wa.y, wa.z, wa.w, wb.x, wb.y, wb.z, wb.w};
            #pragma unroll
            for (int i = 0; i < 8; i++)
                #pragma unroll
                for (int j = 0; j < 8; j++)
                    acc[i][j] += xr[i] * wc[j];
        }

        int row0 = tile * 128;
        #pragma unroll
        for (int i = 0; i < 8; i++) {
            int r = row0 + r0 + i;
            if (r < n) {
                *(float4*)&out[(size_t)r * 128 + c0]     = make_float4(acc[i][0], acc[i][1], acc[i][2], acc[i][3]);
                *(float4*)&out[(size_t)r * 128 + c0 + 4] = make_float4(acc[i][4], acc[i][5], acc[i][6], acc[i][7]);
            }
        }
    }
}

union H16Chunk { float4 f4; __half2 h2[4]; };
union H16Half  { float2 f2; __half2 h2[2]; };

// ---------- g = x16 @ W (fp16 in, fp16 out, no epilogue), persistent -------
__global__ __launch_bounds__(256) void k_gemm16(
    const __half* __restrict__ x16, const float* __restrict__ W,
    __half* __restrict__ g16, int n, int ntiles) {
    __shared__ float Wl[128 * 128];
    __shared__ float Xs[128 * 132];
    int tid = threadIdx.x;

    const float4* W4 = (const float4*)W;
    float4* Wl4 = (float4*)Wl;
    #pragma unroll
    for (int i = 0; i < 16; i++) Wl4[tid + i * 256] = W4[tid + i * 256];

    int c0 = (tid & 15) * 8;
    int r0 = (tid >> 4) * 8;
    int sr = tid >> 1;               // row 0..127
    int sq = (tid & 1) * 8;          // chunk base 0 or 8 (16 chunks of 8 halfs)
    const float4* x4p = (const float4*)x16;   // 16 float4-chunks per 256B row

    float4 pf[8];
    int tile = blockIdx.x;
    if (tile < ntiles) {
        int grow = tile * 128 + sr;
        if (grow < n) {
            #pragma unroll
            for (int j = 0; j < 8; j++) pf[j] = x4p[(size_t)grow * 16 + sq + j];
        }
    }

    for (; tile < ntiles; tile += gridDim.x) {
        __syncthreads();
        {
            int grow = tile * 128 + sr;
            if (grow < n) {
                #pragma unroll
                for (int j = 0; j < 8; j++) {
                    H16Chunk u; u.f4 = pf[j];
                    int kb = (sq + j) * 8;
                    #pragma unroll
                    for (int i = 0; i < 4; i++) {
                        float2 t = __half22float2(u.h2[i]);
                        Xs[(kb + 2 * i + 0) * 132 + sr] = t.x;
                        Xs[(kb + 2 * i + 1) * 132 + sr] = t.y;
                    }
                }
            }
        }
        __syncthreads();

        int ntile = tile + gridDim.x;
        if (ntile < ntiles) {
            int grow = ntile * 128 + sr;
            if (grow < n) {
                #pragma unroll
                for (int j = 0; j < 8; j++) pf[j] = x4p[(size_t)grow * 16 + sq + j];
            }
        }

        float acc[8][8] = {};
        #pragma unroll 2
        for (int k = 0; k < 128; k++) {
            float4 xa = *(const float4*)&Xs[k * 132 + r0];
            float4 xb = *(const float4*)&Xs[k * 132 + r0 + 4];
            float4 wa = *(const float4*)&Wl[k * 128 + c0];
            float4 wb = *(const float4*)&Wl[k * 128 + c0 + 4];
            float xr[8] = {xa.x, xa.y, xa.z, xa.w, xb.x, xb.y, xb.z, xb.w};
            float wc[8] = {wa.x, wa.y, wa.z, wa.w, wb.x, wb.y, wb.z, wb.w};
            #pragma unroll
            for (int i = 0; i < 8; i++)
                #pragma unroll
                for (int j = 0; j < 8; j++)
                    acc[i][j] += xr[i] * wc[j];
        }

        int row0 = tile * 128;
        #pragma unroll
        for (int i = 0; i < 8; i++) {
            int r = row0 + r0 + i;
            if (r < n) {
                H16Chunk u;
                u.h2[0] = __floats2half2_rn(acc[i][0], acc[i][1]);
                u.h2[1] = __floats2half2_rn(acc[i][2], acc[i][3]);
                u.h2[2] = __floats2half2_rn(acc[i][4], acc[i][5]);
                u.h2[3] = __floats2half2_rn(acc[i][6], acc[i][7]);
                *(float4*)&g16[(size_t)r * 128 + c0] = u.f4;
            }
        }
    }
}

// ---------- layer-1: agg over embW (fp32, L2-resident) via ann[src] --------
// h1[v] = relu( inv*(embW[ann[v]] + sum_u embW[ann[u]]) + b1 ) -> fp16
__global__ __launch_bounds__(256) void k_aggW(
    const float4* __restrict__ eW4, const int* __restrict__ ann,
    const int* __restrict__ row_ptr, const int* __restrict__ eidx,
    const float4* __restrict__ bias4, __half* __restrict__ h16, int n) {
    int v = blockIdx.x * 4 + (threadIdx.x >> 6);
    int lane = threadIdx.x & 63;
    int half = lane >> 5;
    int q = lane & 31;
    int beg = row_ptr[v], end = row_ptr[v + 1];
    int deg = end - beg;
    float4 acc = make_float4(0.f, 0.f, 0.f, 0.f);
    if (half == 0) acc = eW4[(size_t)ann[v] * 32 + q];   // self term once

    int pairs = deg >> 1;
    int p = 0;
    for (; p + 8 <= pairs; p += 8) {
        int eb = beg + 2 * p + half;
        int t0 = eidx[eb +  0], t1 = eidx[eb +  2], t2 = eidx[eb +  4], t3 = eidx[eb +  6];
        int t4 = eidx[eb +  8], t5 = eidx[eb + 10], t6 = eidx[eb + 12], t7 = eidx[eb + 14];
        int a0 = ann[t0], a1 = ann[t1], a2 = ann[t2], a3 = ann[t3];
        int a4 = ann[t4], a5 = ann[t5], a6 = ann[t6], a7 = ann[t7];
        float4 w0 = eW4[(size_t)a0 * 32 + q], w1 = eW4[(size_t)a1 * 32 + q];
        float4 w2 = eW4[(size_t)a2 * 32 + q], w3 = eW4[(size_t)a3 * 32 + q];
        float4 w4 = eW4[(size_t)a4 * 32 + q], w5 = eW4[(size_t)a5 * 32 + q];
        float4 w6 = eW4[(size_t)a6 * 32 + q], w7 = eW4[(size_t)a7 * 32 + q];
        acc.x += ((w0.x + w1.x) + (w2.x + w3.x)) + ((w4.x + w5.x) + (w6.x + w7.x));
        acc.y += ((w0.y + w1.y) + (w2.y + w3.y)) + ((w4.y + w5.y) + (w6.y + w7.y));
        acc.z += ((w0.z + w1.z) + (w2.z + w3.z)) + ((w4.z + w5.z) + (w6.z + w7.z));
        acc.w += ((w0.w + w1.w) + (w2.w + w3.w)) + ((w4.w + w5.w) + (w6.w + w7.w));
    }
    for (; p < pairs; p++) {
        int a = ann[eidx[beg + 2 * p + half]];
        float4 w = eW4[(size_t)a * 32 + q];
        acc.x += w.x; acc.y += w.y; acc.z += w.z; acc.w += w.w;
    }
    if ((deg & 1) && half == 0) {
        int a = ann[eidx[end - 1]];
        float4 w = eW4[(size_t)a * 32 + q];
        acc.x += w.x; acc.y += w.y; acc.z += w.z; acc.w += w.w;
    }
    acc.x += __shfl_down(acc.x, 32, 64);
    acc.y += __shfl_down(acc.y, 32, 64);
    acc.z += __shfl_down(acc.z, 32, 64);
    acc.w += __shfl_down(acc.w, 32, 64);
    if (half == 0) {
        float sc = 1.0f / (float)(deg + 1);
        float4 bv = bias4[q];
        H16Half u;
        u.h2[0] = __floats2half2_rn(fmaxf(acc.x * sc + bv.x, 0.f),
                                    fmaxf(acc.y * sc + bv.y, 0.f));
        u.h2[1] = __floats2half2_rn(fmaxf(acc.z * sc + bv.z, 0.f),
                                    fmaxf(acc.w * sc + bv.w, 0.f));
        *(float2*)&h16[(size_t)v * 128 + q * 4] = u.f2;
    }
}

// ---------- layers 2-3: agg over fp16 g rows + fused epilogue --------------
// out = relu(inv*(g[v]+sum g[u]) + b) -> fp16 h16out OR fp32 f32out
__global__ __launch_bounds__(256) void k_agg16e(
    const float4* __restrict__ g4, const int* __restrict__ row_ptr,
    const int* __restrict__ eidx, const float4* __restrict__ bias4,
    __half* __restrict__ h16out, float* __restrict__ f32out, int n) {
    int v = blockIdx.x * 4 + (threadIdx.x >> 6);
    int lane = threadIdx.x & 63;
    int g = lane >> 4;           // group 0..3
    int q = lane & 15;           // 16B chunk within 256B row
    int beg = row_ptr[v], end = row_ptr[v + 1];
    int deg = end - beg;
    float acc[8] = {};

    #define ACCUM(raw) do { H16Chunk u; u.f4 = (raw);                          \
        float2 t0 = __half22float2(u.h2[0]); acc[0] += t0.x; acc[1] += t0.y;   \
        float2 t1 = __half22float2(u.h2[1]); acc[2] += t1.x; acc[3] += t1.y;   \
        float2 t2 = __half22float2(u.h2[2]); acc[4] += t2.x; acc[5] += t2.y;   \
        float2 t3 = __half22float2(u.h2[3]); acc[6] += t3.x; acc[7] += t3.y; } while (0)

    if (g == 0) ACCUM(g4[(size_t)v * 16 + q]);        // self term once

    int quads = deg >> 2;
    int p = 0;
    for (; p + 8 <= quads; p += 8) {
        int eb = beg + 4 * p + g;
        int s0 = eidx[eb +  0], s1 = eidx[eb +  4], s2 = eidx[eb +  8], s3 = eidx[eb + 12];
        int s4 = eidx[eb + 16], s5 = eidx[eb + 20], s6 = eidx[eb + 24], s7 = eidx[eb + 28];
        float4 r0 = g4[(size_t)s0 * 16 + q], r1 = g4[(size_t)s1 * 16 + q];
        float4 r2 = g4[(size_t)s2 * 16 + q], r3 = g4[(size_t)s3 * 16 + q];
        float4 r4 = g4[(size_t)s4 * 16 + q], r5 = g4[(size_t)s5 * 16 + q];
        float4 r6 = g4[(size_t)s6 * 16 + q], r7 = g4[(size_t)s7 * 16 + q];
        ACCUM(r0); ACCUM(r1); ACCUM(r2); ACCUM(r3);
        ACCUM(r4); ACCUM(r5); ACCUM(r6); ACCUM(r7);
    }
    for (; p < quads; p++) ACCUM(g4[(size_t)eidx[beg + 4 * p + g] * 16 + q]);
    int tail = deg & 3;
    if (g < tail) ACCUM(g4[(size_t)eidx[beg + 4 * quads + g] * 16 + q]);
    #undef ACCUM

    #pragma unroll
    for (int j = 0; j < 8; j++) {
        acc[j] += __shfl_down(acc[j], 16, 64);   // g0+=g1, g2+=g3
        acc[j] += __shfl_down(acc[j], 32, 64);   // g0+=g2
    }
    if (g == 0) {
        float sc = 1.0f / (float)(deg + 1);
        float4 b0 = bias4[2 * q], b1 = bias4[2 * q + 1];
        float o[8];
        o[0] = fmaxf(acc[0] * sc + b0.x, 0.f);
        o[1] = fmaxf(acc[1] * sc + b0.y, 0.f);
        o[2] = fmaxf(acc[2] * sc + b0.z, 0.f);
        o[3] = fmaxf(acc[3] * sc + b0.w, 0.f);
        o[4] = fmaxf(acc[4] * sc + b1.x, 0.f);
        o[5] = fmaxf(acc[5] * sc + b1.y, 0.f);
        o[6] = fmaxf(acc[6] * sc + b1.z, 0.f);
        o[7] = fmaxf(acc[7] * sc + b1.w, 0.f);
        if (h16out) {
            H16Chunk u;
            u.h2[0] = __floats2half2_rn(o[0], o[1]);
            u.h2[1] = __floats2half2_rn(o[2], o[3]);
            u.h2[2] = __floats2half2_rn(o[4], o[5]);
            u.h2[3] = __floats2half2_rn(o[6], o[7]);
            *(float4*)&h16out[(size_t)v * 128 + q * 8] = u.f4;
        } else {
            *(float4*)&f32out[(size_t)v * 128 + q * 8]     = make_float4(o[0], o[1], o[2], o[3]);
            *(float4*)&f32out[(size_t)v * 128 + q * 8 + 4] = make_float4(o[4], o[5], o[6], o[7]);
        }
    }
}

extern "C" void kernel_launch(void* const* d_in, const int* in_sizes, int n_in,
                              void* d_out, int out_size, void* d_ws, size_t ws_size,
                              hipStream_t stream) {
    const int*   ann = (const int*)d_in[0];
    const int*   src = (const int*)d_in[1];
    const int*   dst = (const int*)d_in[2];
    const float* emb = (const float*)d_in[3];
    const float* Ws  = (const float*)d_in[4];
    const float* bs  = (const float*)d_in[5];
    float* out = (float*)d_out;

    const int N = in_sizes[0];          // 100000
    const int E = in_sizes[1];          // 1600000
    const int V = in_sizes[3] / D;      // 5000
    const int NB  = (N + 255) / 256;    // 391
    const int NT  = (N + 127) / 128;    // 782
    const int NTV = (V + 127) / 128;    // 40

    // ws: deg/cur [N] | row_ptr [N+1] | bsum [512] | eidx [E]
    //     | hA16 [N*D f16] | gB16 [N*D f16] | embW [V*D f32]   (~61 MB)
    int* deg     = (int*)d_ws;
    int* row_ptr = deg + ((N + 3) & ~3);
    int* bsum    = row_ptr + ((N + 1 + 3) & ~3);
    int* eidx    = bsum + 512;
    __half* hA16 = (__half*)(eidx + ((E + 3) & ~3));
    __half* gB16 = hA16 + (size_t)N * D;
    float*  embW = (float*)(gB16 + (size_t)N * D);

    // --- embW = emb @ W1 (tiny; independent of CSR) ---
    k_gemm_plain<<<NTV, 256, 0, stream>>>(emb, Ws, embW, V, NTV);

    // --- CSR build (once; reused by all 3 layers) ---
    hipMemsetAsync(deg, 0, (size_t)N * sizeof(int), stream);
    k_count<<<(E + 255) / 256, 256, 0, stream>>>(dst, deg, E);
    k_bsum<<<NB, 256, 0, stream>>>(deg, bsum, N);
    k_scanb<<<1, 512, 0, stream>>>(bsum, NB, row_ptr, N, E);
    k_scan_local<<<NB, 256, 0, stream>>>(deg, bsum, row_ptr, N);
    hipMemsetAsync(deg, 0, (size_t)N * sizeof(int), stream);   // reuse as cursor
    k_fill<<<(E + 255) / 256, 256, 0, stream>>>(src, dst, row_ptr, deg, eidx, E);
    k_sort<<<NB, 256, 0, stream>>>(row_ptr, eidx, N);

    // --- layer 1: fused agg over embW -> h1 (fp16) ---
    k_aggW<<<N / 4, 256, 0, stream>>>((const float4*)embW, ann, row_ptr, eidx,
                                      (const float4*)bs, hA16, N);

    // --- layer 2: g1 = h1@W2 (fp16); fused agg -> h2 (fp16) ---
    k_gemm16<<<256, 256, 0, stream>>>(hA16, Ws + (size_t)D * D, gB16, N, NT);
    k_agg16e<<<N / 4, 256, 0, stream>>>((const float4*)gB16, row_ptr, eidx,
                                        (const float4*)(bs + D), hA16, nullptr, N);

    // --- layer 3: g2 = h2@W3 (fp16); fused agg -> out (fp32) ---
    k_gemm16<<<256, 256, 0, stream>>>(hA16, Ws + (size_t)2 * D * D, gB16, N, NT);
    k_agg16e<<<N / 4, 256, 0, stream>>>((const float4*)gB16, row_ptr, eidx,
                                        (const float4*)(bs + 2 * D), nullptr, out, N);
}

// Round 9
// 584.180 us; speedup vs baseline: 1.3012x; 1.3012x over previous
//
#include <hip/hip_runtime.h>
#include <hip/hip_fp16.h>

// Graph_NN: 3-layer SAGE (gcn aggregator), N=100000, E=1600000, D=128, fp32.
// R9 = R7 structure + R8's fused project-then-aggregate, minus R8's regressions:
//   - NO k_sort (cost ~100us, zero agg benefit measured in R8)
//   - k_fill writes int2 (src, ann[src]) per edge (scattered cost is per-LINE,
//     not per-byte: 4B and 8B both dirty one 64B line; int2 feeds both aggs)
//   - k_agg16e quads loop unrolled x4: avg deg=16 -> quads=4 -> exactly one
//     unrolled iteration with 16 rows in flight (R8's x8 unroll needed deg>=32
//     and nearly always fell into the serial remainder loop)
// Pipeline: embW=emb@W1 (V rows); L1: fused agg over embW -> h16;
// L2/L3: g=h16@W (fp16 GEMM) then fused agg+bias+relu epilogue.

#define D 128

// ---------- CSR build ----------
__global__ void k_count(const int* __restrict__ dst, int* __restrict__ deg, int E) {
    int e = blockIdx.x * blockDim.x + threadIdx.x;
    if (e < E) atomicAdd(&deg[dst[e]], 1);
}

__global__ void k_bsum(const int* __restrict__ deg, int* __restrict__ bsum, int n) {
    __shared__ int s[256];
    int t = threadIdx.x, i = blockIdx.x * 256 + t;
    s[t] = (i < n) ? deg[i] : 0;
    __syncthreads();
    for (int off = 128; off > 0; off >>= 1) { if (t < off) s[t] += s[t + off]; __syncthreads(); }
    if (t == 0) bsum[blockIdx.x] = s[0];
}

__global__ void k_scanb(int* __restrict__ bsum, int nb, int* __restrict__ row_ptr, int N, int E) {
    __shared__ int s[512];
    int t = threadIdx.x;
    int v = (t < nb) ? bsum[t] : 0;
    s[t] = v;
    __syncthreads();
    for (int off = 1; off < 512; off <<= 1) {
        int x = (t >= off) ? s[t - off] : 0;
        __syncthreads();
        s[t] += x;
        __syncthreads();
    }
    if (t < nb) bsum[t] = s[t] - v;          // exclusive prefix
    if (t == 0) row_ptr[N] = E;
}

__global__ void k_scan_local(const int* __restrict__ deg, const int* __restrict__ bpre,
                             int* __restrict__ row_ptr, int n) {
    __shared__ int s[256];
    int t = threadIdx.x, i = blockIdx.x * 256 + t;
    int v = (i < n) ? deg[i] : 0;
    s[t] = v;
    __syncthreads();
    for (int off = 1; off < 256; off <<= 1) {
        int x = (t >= off) ? s[t - off] : 0;
        __syncthreads();
        s[t] += x;
        __syncthreads();
    }
    if (i < n) row_ptr[i] = bpre[blockIdx.x] + s[t] - v;   // exclusive
}

// fill eal[pos] = (src, ann[src]) grouped by dst — single 8B scattered write
__global__ void k_fill(const int* __restrict__ src, const int* __restrict__ dst,
                       const int* __restrict__ ann, const int* __restrict__ row_ptr,
                       int* __restrict__ cur, int2* __restrict__ eal, int E) {
    int e = blockIdx.x * blockDim.x + threadIdx.x;
    if (e >= E) return;
    int d = dst[e];
    int s = src[e];
    int pos = atomicAdd(&cur[d], 1);
    eal[row_ptr[d] + pos] = make_int2(s, ann[s]);
}

// ---------- small plain GEMM: out = x @ W (fp32 in/out, V rows) ------------
__global__ __launch_bounds__(256) void k_gemm_plain(
    const float* __restrict__ x, const float* __restrict__ W,
    float* __restrict__ out, int n, int ntiles) {
    __shared__ float Wl[128 * 128];
    __shared__ float Xs[128 * 132];
    int tid = threadIdx.x;

    const float4* W4 = (const float4*)W;
    float4* Wl4 = (float4*)Wl;
    #pragma unroll
    for (int i = 0; i < 16; i++) Wl4[tid + i * 256] = W4[tid + i * 256];

    int c0 = (tid & 15) * 8;
    int r0 = (tid >> 4) * 8;
    int sr = tid >> 1;
    int sq = (tid & 1) * 16;
    const float4* x4p = (const float4*)x;

    for (int tile = blockIdx.x; tile < ntiles; tile += gridDim.x) {
        __syncthreads();
        {
            int grow = tile * 128 + sr;
            if (grow < n) {
                #pragma unroll
                for (int j = 0; j < 16; j++) {
                    int q = sq + j;
                    float4 v = x4p[(size_t)grow * 32 + q];
                    Xs[(q * 4 + 0) * 132 + sr] = v.x;
                    Xs[(q * 4 + 1) * 132 + sr] = v.y;
                    Xs[(q * 4 + 2) * 132 + sr] = v.z;
                    Xs[(q * 4 + 3) * 132 + sr] = v.w;
                }
            }
        }
        __syncthreads();

        float acc[8][8] = {};
        #pragma unroll 2
        for (int k = 0; k < 128; k++) {
            float4 xa = *(const float4*)&Xs[k * 132 + r0];
            float4 xb = *(const float4*)&Xs[k * 132 + r0 + 4];
            float4 wa = *(const float4*)&Wl[k * 128 + c0];
            float4 wb = *(const float4*)&Wl[k * 128 + c0 + 4];
            float xr[8] = {xa.x, xa.y, xa.z, xa.w, xb.x, xb.y, xb.z, xb.w};
            float wc[8] = {wa.x, wa.y, wa.z, wa.w, wb.x, wb.y, wb.z, wb.w};
            #pragma unroll
            for (int i = 0; i < 8; i++)
                #pragma unroll
                for (int j = 0; j < 8; j++)
                    acc[i][j] += xr[i] * wc[j];
        }

        int row0 = tile * 128;
        #pragma unroll
        for (int i = 0; i < 8; i++) {
            int r = row0 + r0 + i;
            if (r < n) {
                *(float4*)&out[(size_t)r * 128 + c0]     = make_float4(acc[i][0], acc[i][1], acc[i][2], acc[i][3]);
                *(float4*)&out[(size_t)r * 128 + c0 + 4] = make_float4(acc[i][4], acc[i][5], acc[i][6], acc[i][7]);
            }
        }
    }
}

union H16Chunk { float4 f4; __half2 h2[4]; };
union H16Half  { float2 f2; __half2 h2[2]; };

// ---------- g = x16 @ W (fp16 in, fp16 out, no epilogue), persistent -------
__global__ __launch_bounds__(256) void k_gemm16(
    const __half* __restrict__ x16, const float* __restrict__ W,
    __half* __restrict__ g16, int n, int ntiles) {
    __shared__ float Wl[128 * 128];
    __shared__ float Xs[128 * 132];
    int tid = threadIdx.x;

    const float4* W4 = (const float4*)W;
    float4* Wl4 = (float4*)Wl;
    #pragma unroll
    for (int i = 0; i < 16; i++) Wl4[tid + i * 256] = W4[tid + i * 256];

    int c0 = (tid & 15) * 8;
    int r0 = (tid >> 4) * 8;
    int sr = tid >> 1;               // row 0..127
    int sq = (tid & 1) * 8;          // chunk base 0 or 8 (16 chunks of 8 halfs)
    const float4* x4p = (const float4*)x16;   // 16 float4-chunks per 256B row

    float4 pf[8];
    int tile = blockIdx.x;
    if (tile < ntiles) {
        int grow = tile * 128 + sr;
        if (grow < n) {
            #pragma unroll
            for (int j = 0; j < 8; j++) pf[j] = x4p[(size_t)grow * 16 + sq + j];
        }
    }

    for (; tile < ntiles; tile += gridDim.x) {
        __syncthreads();
        {
            int grow = tile * 128 + sr;
            if (grow < n) {
                #pragma unroll
                for (int j = 0; j < 8; j++) {
                    H16Chunk u; u.f4 = pf[j];
                    int kb = (sq + j) * 8;
                    #pragma unroll
                    for (int i = 0; i < 4; i++) {
                        float2 t = __half22float2(u.h2[i]);
                        Xs[(kb + 2 * i + 0) * 132 + sr] = t.x;
                        Xs[(kb + 2 * i + 1) * 132 + sr] = t.y;
                    }
                }
            }
        }
        __syncthreads();

        int ntile = tile + gridDim.x;
        if (ntile < ntiles) {
            int grow = ntile * 128 + sr;
            if (grow < n) {
                #pragma unroll
                for (int j = 0; j < 8; j++) pf[j] = x4p[(size_t)grow * 16 + sq + j];
            }
        }

        float acc[8][8] = {};
        #pragma unroll 2
        for (int k = 0; k < 128; k++) {
            float4 xa = *(const float4*)&Xs[k * 132 + r0];
            float4 xb = *(const float4*)&Xs[k * 132 + r0 + 4];
            float4 wa = *(const float4*)&Wl[k * 128 + c0];
            float4 wb = *(const float4*)&Wl[k * 128 + c0 + 4];
            float xr[8] = {xa.x, xa.y, xa.z, xa.w, xb.x, xb.y, xb.z, xb.w};
            float wc[8] = {wa.x, wa.y, wa.z, wa.w, wb.x, wb.y, wb.z, wb.w};
            #pragma unroll
            for (int i = 0; i < 8; i++)
                #pragma unroll
                for (int j = 0; j < 8; j++)
                    acc[i][j] += xr[i] * wc[j];
        }

        int row0 = tile * 128;
        #pragma unroll
        for (int i = 0; i < 8; i++) {
            int r = row0 + r0 + i;
            if (r < n) {
                H16Chunk u;
                u.h2[0] = __floats2half2_rn(acc[i][0], acc[i][1]);
                u.h2[1] = __floats2half2_rn(acc[i][2], acc[i][3]);
                u.h2[2] = __floats2half2_rn(acc[i][4], acc[i][5]);
                u.h2[3] = __floats2half2_rn(acc[i][6], acc[i][7]);
                *(float4*)&g16[(size_t)r * 128 + c0] = u.f4;
            }
        }
    }
}

// ---------- layer-1: agg over embW (fp32, L2-resident) via eal.y -----------
// h1[v] = relu( inv*(embW[ann[v]] + sum_u embW[ann[u]]) + b1 ) -> fp16
__global__ __launch_bounds__(256) void k_aggW(
    const float4* __restrict__ eW4, const int* __restrict__ ann,
    const int* __restrict__ row_ptr, const int2* __restrict__ eal,
    const float4* __restrict__ bias4, __half* __restrict__ h16, int n) {
    int v = blockIdx.x * 4 + (threadIdx.x >> 6);
    int lane = threadIdx.x & 63;
    int half = lane >> 5;
    int q = lane & 31;
    int beg = row_ptr[v], end = row_ptr[v + 1];
    int deg = end - beg;
    float4 acc = make_float4(0.f, 0.f, 0.f, 0.f);
    if (half == 0) acc = eW4[(size_t)ann[v] * 32 + q];   // self term once

    int pairs = deg >> 1;
    int p = 0;
    for (; p + 4 <= pairs; p += 4) {    // deg>=8 hits this; 8 rows in flight
        int eb = beg + 2 * p + half;
        int a0 = eal[eb + 0].y, a1 = eal[eb + 2].y, a2 = eal[eb + 4].y, a3 = eal[eb + 6].y;
        float4 w0 = eW4[(size_t)a0 * 32 + q], w1 = eW4[(size_t)a1 * 32 + q];
        float4 w2 = eW4[(size_t)a2 * 32 + q], w3 = eW4[(size_t)a3 * 32 + q];
        acc.x += (w0.x + w1.x) + (w2.x + w3.x);
        acc.y += (w0.y + w1.y) + (w2.y + w3.y);
        acc.z += (w0.z + w1.z) + (w2.z + w3.z);
        acc.w += (w0.w + w1.w) + (w2.w + w3.w);
    }
    for (; p < pairs; p++) {
        int a = eal[beg + 2 * p + half].y;
        float4 w = eW4[(size_t)a * 32 + q];
        acc.x += w.x; acc.y += w.y; acc.z += w.z; acc.w += w.w;
    }
    if ((deg & 1) && half == 0) {
        int a = eal[end - 1].y;
        float4 w = eW4[(size_t)a * 32 + q];
        acc.x += w.x; acc.y += w.y; acc.z += w.z; acc.w += w.w;
    }
    acc.x += __shfl_down(acc.x, 32, 64);
    acc.y += __shfl_down(acc.y, 32, 64);
    acc.z += __shfl_down(acc.z, 32, 64);
    acc.w += __shfl_down(acc.w, 32, 64);
    if (half == 0) {
        float sc = 1.0f / (float)(deg + 1);
        float4 bv = bias4[q];
        H16Half u;
        u.h2[0] = __floats2half2_rn(fmaxf(acc.x * sc + bv.x, 0.f),
                                    fmaxf(acc.y * sc + bv.y, 0.f));
        u.h2[1] = __floats2half2_rn(fmaxf(acc.z * sc + bv.z, 0.f),
                                    fmaxf(acc.w * sc + bv.w, 0.f));
        *(float2*)&h16[(size_t)v * 128 + q * 4] = u.f2;
    }
}

// ---------- layers 2-3: agg over fp16 g rows + fused epilogue --------------
// out = relu(inv*(g[v]+sum g[u]) + b) -> fp16 h16out OR fp32 f32out
// 4 groups x 16 lanes; 1 instr = 4 rows; quads-loop unroll 4 -> deg=16 runs
// exactly one unrolled iteration with 16 rows in flight.
__global__ __launch_bounds__(256) void k_agg16e(
    const float4* __restrict__ g4, const int* __restrict__ row_ptr,
    const int2* __restrict__ eal, const float4* __restrict__ bias4,
    __half* __restrict__ h16out, float* __restrict__ f32out, int n) {
    int v = blockIdx.x * 4 + (threadIdx.x >> 6);
    int lane = threadIdx.x & 63;
    int g = lane >> 4;           // group 0..3
    int q = lane & 15;           // 16B chunk within 256B row
    int beg = row_ptr[v], end = row_ptr[v + 1];
    int deg = end - beg;
    float acc[8] = {};

    #define ACCUM(raw) do { H16Chunk u; u.f4 = (raw);                          \
        float2 t0 = __half22float2(u.h2[0]); acc[0] += t0.x; acc[1] += t0.y;   \
        float2 t1 = __half22float2(u.h2[1]); acc[2] += t1.x; acc[3] += t1.y;   \
        float2 t2 = __half22float2(u.h2[2]); acc[4] += t2.x; acc[5] += t2.y;   \
        float2 t3 = __half22float2(u.h2[3]); acc[6] += t3.x; acc[7] += t3.y; } while (0)

    if (g == 0) ACCUM(g4[(size_t)v * 16 + q]);        // self term once

    int quads = deg >> 2;
    int p = 0;
    for (; p + 4 <= quads; p += 4) {   // deg>=16: 16 rows in flight per wave
        int eb = beg + 4 * p + g;
        int s0 = eal[eb +  0].x, s1 = eal[eb +  4].x;
        int s2 = eal[eb +  8].x, s3 = eal[eb + 12].x;
        float4 r0 = g4[(size_t)s0 * 16 + q], r1 = g4[(size_t)s1 * 16 + q];
        float4 r2 = g4[(size_t)s2 * 16 + q], r3 = g4[(size_t)s3 * 16 + q];
        ACCUM(r0); ACCUM(r1); ACCUM(r2); ACCUM(r3);
    }
    for (; p < quads; p++) ACCUM(g4[(size_t)eal[beg + 4 * p + g].x * 16 + q]);
    int tail = deg & 3;
    if (g < tail) ACCUM(g4[(size_t)eal[beg + 4 * quads + g].x * 16 + q]);
    #undef ACCUM

    #pragma unroll
    for (int j = 0; j < 8; j++) {
        acc[j] += __shfl_down(acc[j], 16, 64);   // g0+=g1, g2+=g3
        acc[j] += __shfl_down(acc[j], 32, 64);   // g0+=g2
    }
    if (g == 0) {
        float sc = 1.0f / (float)(deg + 1);
        float4 b0 = bias4[2 * q], b1 = bias4[2 * q + 1];
        float o[8];
        o[0] = fmaxf(acc[0] * sc + b0.x, 0.f);
        o[1] = fmaxf(acc[1] * sc + b0.y, 0.f);
        o[2] = fmaxf(acc[2] * sc + b0.z, 0.f);
        o[3] = fmaxf(acc[3] * sc + b0.w, 0.f);
        o[4] = fmaxf(acc[4] * sc + b1.x, 0.f);
        o[5] = fmaxf(acc[5] * sc + b1.y, 0.f);
        o[6] = fmaxf(acc[6] * sc + b1.z, 0.f);
        o[7] = fmaxf(acc[7] * sc + b1.w, 0.f);
        if (h16out) {
            H16Chunk u;
            u.h2[0] = __floats2half2_rn(o[0], o[1]);
            u.h2[1] = __floats2half2_rn(o[2], o[3]);
            u.h2[2] = __floats2half2_rn(o[4], o[5]);
            u.h2[3] = __floats2half2_rn(o[6], o[7]);
            *(float4*)&h16out[(size_t)v * 128 + q * 8] = u.f4;
        } else {
            *(float4*)&f32out[(size_t)v * 128 + q * 8]     = make_float4(o[0], o[1], o[2], o[3]);
            *(float4*)&f32out[(size_t)v * 128 + q * 8 + 4] = make_float4(o[4], o[5], o[6], o[7]);
        }
    }
}

extern "C" void kernel_launch(void* const* d_in, const int* in_sizes, int n_in,
                              void* d_out, int out_size, void* d_ws, size_t ws_size,
                              hipStream_t stream) {
    const int*   ann = (const int*)d_in[0];
    const int*   src = (const int*)d_in[1];
    const int*   dst = (const int*)d_in[2];
    const float* emb = (const float*)d_in[3];
    const float* Ws  = (const float*)d_in[4];
    const float* bs  = (const float*)d_in[5];
    float* out = (float*)d_out;

    const int N = in_sizes[0];          // 100000
    const int E = in_sizes[1];          // 1600000
    const int V = in_sizes[3] / D;      // 5000
    const int NB  = (N + 255) / 256;    // 391
    const int NT  = (N + 127) / 128;    // 782
    const int NTV = (V + 127) / 128;    // 40

    // ws: deg/cur [N] | row_ptr [N+1] | bsum [512] | eal [int2 E]
    //     | hA16 [N*D f16] | gB16 [N*D f16] | embW [V*D f32]   (~67 MB)
    int*  deg     = (int*)d_ws;
    int*  row_ptr = deg + ((N + 3) & ~3);
    int*  bsum    = row_ptr + ((N + 1 + 3) & ~3);
    int2* eal     = (int2*)(bsum + 512);
    __half* hA16  = (__half*)(eal + E);
    __half* gB16  = hA16 + (size_t)N * D;
    float*  embW  = (float*)(gB16 + (size_t)N * D);

    // --- embW = emb @ W1 (tiny; independent of CSR) ---
    k_gemm_plain<<<NTV, 256, 0, stream>>>(emb, Ws, embW, V, NTV);

    // --- CSR build (once; reused by all 3 layers) ---
    hipMemsetAsync(deg, 0, (size_t)N * sizeof(int), stream);
    k_count<<<(E + 255) / 256, 256, 0, stream>>>(dst, deg, E);
    k_bsum<<<NB, 256, 0, stream>>>(deg, bsum, N);
    k_scanb<<<1, 512, 0, stream>>>(bsum, NB, row_ptr, N, E);
    k_scan_local<<<NB, 256, 0, stream>>>(deg, bsum, row_ptr, N);
    hipMemsetAsync(deg, 0, (size_t)N * sizeof(int), stream);   // reuse as cursor
    k_fill<<<(E + 255) / 256, 256, 0, stream>>>(src, dst, ann, row_ptr, deg, eal, E);

    // --- layer 1: fused agg over embW -> h1 (fp16) ---
    k_aggW<<<N / 4, 256, 0, stream>>>((const float4*)embW, ann, row_ptr, eal,
                                      (const float4*)bs, hA16, N);

    // --- layer 2: g1 = h1@W2 (fp16); fused agg -> h2 (fp16) ---
    k_gemm16<<<256, 256, 0, stream>>>(hA16, Ws + (size_t)D * D, gB16, N, NT);
    k_agg16e<<<N / 4, 256, 0, stream>>>((const float4*)gB16, row_ptr, eal,
                                        (const float4*)(bs + D), hA16, nullptr, N);

    // --- layer 3: g2 = h2@W3 (fp16); fused agg -> out (fp32) ---
    k_gemm16<<<256, 256, 0, stream>>>(hA16, Ws + (size_t)2 * D * D, gB16, N, NT);
    k_agg16e<<<N / 4, 256, 0, stream>>>((const float4*)gB16, row_ptr, eal,
                                        (const float4*)(bs + 2 * D), nullptr, out, N);
}